// Round 5
// baseline (236.874 us; speedup 1.0000x reference)
//
#include <hip/hip_runtime.h>
#include <hip/hip_bf16.h>

// Problem: MLP_AE_72756745994415
// out[k,i] depends only on j = i/10 (reference drops the ones digit):
//   j>=1000: T4A[j/100]*B4[j%100]; j>=100: T3A[j/10]*B3[j%10];
//   j>=10: T2A[j]; j in 1..9: x3[1]*x3[5+j]; j==0: i==0 -> x3[1]*x3[5], else x3[0]
//
// R5: MLP processes 2 batch rows per block (256 blocks x 512 thr) so each
// loaded w2 fragment is used for BOTH rows -> w2 L2 traffic 256->128 MB.
// Expand kernel unchanged from R3/R4 (at its 205 MB store floor).

#define BATCH 512
#define DIM   512
#define HID   256
#define NCLS  55
#define NOUT  99999
#define LEAK  0.01f

__global__ __launch_bounds__(512) void mlp_x3_kernel(
    const float* __restrict__ x,  const float* __restrict__ w2,
    const float* __restrict__ b2, const float* __restrict__ w3,
    const float* __restrict__ b3, float* __restrict__ x3out) {
    __shared__ float xs[2][DIM];
    __shared__ float hs[2][HID];
    __shared__ float x3s[2][NCLS];

    const int tid  = threadIdx.x;
    const int k2   = blockIdx.x;        // row pair: rows 2*k2, 2*k2+1
    const int wave = tid >> 6;          // 0..7
    const int lane = tid & 63;

    // stage both x rows (1024 floats = 256 float4, threads 0..255)
    if (tid < 256)
        ((float4*)xs)[tid] = ((const float4*)(x + (size_t)k2 * 2 * DIM))[tid];
    __syncthreads();

    // ---- layer 1: wave w computes neurons [32w, 32w+32) for BOTH rows ----
    {
        const float4* xr0 = (const float4*)xs[0];
        const float4* xr1 = (const float4*)xs[1];
        float4 x0a = xr0[lane], x0b = xr0[lane + 64];   // row0 dims [4l..], [256+4l..]
        float4 x1a = xr1[lane], x1b = xr1[lane + 64];   // row1
        float acc0 = 0.f, acc1 = 0.f;
#pragma unroll 4
        for (int t = 0; t < 32; ++t) {
            const int n = wave * 32 + t;
            const float4* w2r = (const float4*)(w2 + (size_t)n * DIM);
            float4 a = w2r[lane];        // contiguous 1 KB across the wave
            float4 b = w2r[lane + 64];
            float s0 = a.x * x0a.x + a.y * x0a.y + a.z * x0a.z + a.w * x0a.w
                     + b.x * x0b.x + b.y * x0b.y + b.z * x0b.z + b.w * x0b.w;
            float s1 = a.x * x1a.x + a.y * x1a.y + a.z * x1a.z + a.w * x1a.w
                     + b.x * x1b.x + b.y * x1b.y + b.z * x1b.z + b.w * x1b.w;
#pragma unroll
            for (int off = 1; off < 64; off <<= 1) {
                s0 += __shfl_xor(s0, off, 64);
                s1 += __shfl_xor(s1, off, 64);
            }
            if (lane == t) { acc0 = s0; acc1 = s1; }
        }
        if (lane < 32) {
            const int n = wave * 32 + lane;
            float bb = b2[n];
            float h0 = acc0 + bb, h1 = acc1 + bb;
            hs[0][n] = (h0 >= 0.f) ? h0 : LEAK * h0;
            hs[1][n] = (h1 >= 0.f) ? h1 : LEAK * h1;
        }
    }
    __syncthreads();

    // ---- layer 2: wave w -> row r=w&1, outputs o = w>>1, +4, ... ----
    {
        const int r = wave & 1;
        float4 hv = ((const float4*)hs[r])[lane];   // dims [4l, 4l+4)
        for (int o = wave >> 1; o < NCLS; o += 4) {
            const float4* w3r = (const float4*)(w3 + (size_t)o * HID);
            float4 w = w3r[lane];
            float s = w.x * hv.x + w.y * hv.y + w.z * hv.z + w.w * hv.w;
#pragma unroll
            for (int off = 1; off < 64; off <<= 1) s += __shfl_xor(s, off, 64);
            if (lane == 0) x3s[r][o] = s + b3[o];
        }
    }
    __syncthreads();

    // ---- softmax: 2 rows x 6 groups ----
    if (tid < 12) {
        int r = tid / 6, g = tid % 6;
        int off = (g == 0) ? 0 : 5 + 10 * (g - 1);
        int len = (g == 0) ? 5 : 10;
        float m = -1e30f;
        for (int u = 0; u < len; ++u) m = fmaxf(m, x3s[r][off + u]);
        float s = 0.f;
        for (int u = 0; u < len; ++u) {
            float e = __expf(x3s[r][off + u] - m);
            x3s[r][off + u] = e;
            s += e;
        }
        float inv = 1.f / s;
        for (int u = 0; u < len; ++u) x3s[r][off + u] *= inv;
    }
    __syncthreads();

    if (tid < 2 * NCLS) {
        int r = tid / NCLS, o = tid % NCLS;
        x3out[(size_t)(k2 * 2 + r) * NCLS + o] = x3s[r][o];
    }
}

__device__ __forceinline__ float Vj(
    unsigned j, const float* __restrict__ T4A, const float* __restrict__ T3A,
    const float* __restrict__ T2A, const float* __restrict__ B4,
    const float* __restrict__ B3,  const float* __restrict__ A1b) {
    if (j >= 1000u) { unsigned q = j / 100u; return T4A[q] * B4[j - q * 100u]; }
    if (j >= 100u)  { unsigned q = j / 10u;  return T3A[q] * B3[j - q * 10u]; }
    if (j >= 10u)   return T2A[j];
    return A1b[j];
}

// 512 rows x 8 slices; each slice covers in-row elements [s*12500, ...).
__global__ __launch_bounds__(256) void expand_kernel(
    const float* __restrict__ x3g, float* __restrict__ out) {
    __shared__ float T4A[100], T3A[100], T2A[100], B4[100];
    __shared__ float B3[16], A1b[16];
    __shared__ float x3s[NCLS];

    const int tid = threadIdx.x;
    const int k   = blockIdx.x >> 3;
    const int s   = blockIdx.x & 7;

    if (tid < NCLS) x3s[tid] = x3g[k * NCLS + tid];
    __syncthreads();

    if (tid < 100) {
        int hi = tid / 10, lo = tid % 10;
        float pp = x3s[5 + hi] * x3s[15 + lo];
        T4A[tid] = x3s[4] * pp;
        T3A[tid] = x3s[3] * pp;
        T2A[tid] = x3s[2] * pp;
        B4[tid]  = x3s[25 + hi] * x3s[35 + lo];
    } else if (tid < 110) {
        int d = tid - 100;
        B3[d]  = x3s[25 + d];
        A1b[d] = (d == 0) ? x3s[0] : x3s[1] * x3s[5 + d];
    }
    __syncthreads();

    const float pz = x3s[1] * x3s[5];   // the i==0 special value

    const unsigned e_lo = (unsigned)s * 12500u;
    const unsigned n_el = (s == 7) ? 12499u : 12500u;
    const size_t   gbase = (size_t)k * NOUT + e_lo;
    const unsigned head = (unsigned)((4u - ((unsigned)gbase & 3u)) & 3u);
    const unsigned ng   = (n_el - head) >> 2;
    const unsigned tail0 = head + (ng << 2);

    if (tid < (int)head) {
        unsigned i = e_lo + (unsigned)tid;
        float v = Vj(i / 10u, T4A, T3A, T2A, B4, B3, A1b);
        if (i == 0u) v = pz;
        out[gbase + tid] = v;
    }
    if (tid < (int)(n_el - tail0)) {
        unsigned e = tail0 + (unsigned)tid;
        unsigned i = e_lo + e;
        out[gbase + e] = Vj(i / 10u, T4A, T3A, T2A, B4, B3, A1b);
    }

    float4* outv = (float4*)(out + gbase + head);
    for (unsigned g = tid; g < ng; g += 256) {
        unsigned i   = e_lo + head + (g << 2);
        unsigned j0  = i / 10u;
        unsigned rem = i - j0 * 10u;          // 0..9
        float v0 = Vj(j0, T4A, T3A, T2A, B4, B3, A1b);
        unsigned j1 = j0 + (rem >= 7u ? 1u : 0u);
        float v1 = Vj(j1, T4A, T3A, T2A, B4, B3, A1b);
        unsigned m = 10u - rem;               // elements using v0 (>=1)
        float4 v;
        v.x = (i == 0u) ? pz : v0;
        v.y = (1u < m) ? v0 : v1;
        v.z = (2u < m) ? v0 : v1;
        v.w = (3u < m) ? v0 : v1;
        outv[g] = v;
    }
}

extern "C" void kernel_launch(void* const* d_in, const int* in_sizes, int n_in,
                              void* d_out, int out_size, void* d_ws, size_t ws_size,
                              hipStream_t stream) {
    const float* x  = (const float*)d_in[0];
    const float* w2 = (const float*)d_in[1];
    const float* b2 = (const float*)d_in[2];
    const float* w3 = (const float*)d_in[3];
    const float* b3 = (const float*)d_in[4];
    float* out = (float*)d_out;
    float* x3  = (float*)d_ws;   // 512*55*4 = 112,640 B

    mlp_x3_kernel<<<BATCH / 2, 512, 0, stream>>>(x, w2, b2, w3, b3, x3);
    expand_kernel<<<BATCH * 8, 256, 0, stream>>>(x3, out);
}